// Round 7
// baseline (360.455 us; speedup 1.0000x reference)
//
#include <hip/hip_runtime.h>
#include <cstdint>
#include <cstddef>

#define BB 256
#define TT 128
#define AA 4
#define II 128
#define HH 256
#define K3 768  // 3*H

typedef __attribute__((ext_vector_type(8))) short short8;
typedef __attribute__((ext_vector_type(4))) float f32x4;
typedef __attribute__((ext_vector_type(4))) unsigned short ushort4_t;

// workgroup barrier draining ONLY lgkmcnt (LDS), not vmcnt.
#define LGKM_BARRIER() asm volatile("s_waitcnt lgkmcnt(0)\n\ts_barrier" ::: "memory")

static __device__ __forceinline__ unsigned short f2bf(float f) {
  unsigned int b = __float_as_uint(f);
  return (unsigned short)((b + 0x7FFFu + ((b >> 16) & 1u)) >> 16);  // RNE
}
static __device__ __forceinline__ float bf2f(unsigned short u) {
  return __uint_as_float(((unsigned int)u) << 16);
}

// fp32 -> bf16 weight conversion into workspace (W_ih then W_hh, row-major kept)
__global__ void wconv_kernel(const float* __restrict__ wih,
                             const float* __restrict__ whh,
                             unsigned short* __restrict__ o) {
  int i = blockIdx.x * 512 + threadIdx.x;
  float v = (i < K3 * II) ? wih[i] : whh[i - K3 * II];
  o[i] = f2bf(v);
}

// ---------------- Phase A: gi = x * W_ih^T + b_ih (+ b_hh for r,z), bf16 ----
__global__ __launch_bounds__(512, 2) void gi_kernel(
    const float* __restrict__ x,
    const float* __restrict__ bih_g,
    const float* __restrict__ bhh_g,
    const unsigned short* __restrict__ wb,   // W_ih bf16 at ws[0]
    unsigned short* __restrict__ gi) {
  __shared__ alignas(16) unsigned short xs[64][144];
  __shared__ alignas(16) unsigned short gst[16][792];
  __shared__ float bihs[K3];

  const int tid = threadIdx.x;
  const int l = tid & 63, w = tid >> 6;
  const int c = l & 15, g = l >> 4;
  const size_t m0 = (size_t)blockIdx.x * 64;

  for (int i = tid; i < K3; i += 512)
    bihs[i] = bih_g[i] + (i < 2 * HH ? bhh_g[i] : 0.f);
  for (int i = tid; i < 64 * 128; i += 512) {
    int row = i >> 7, col = i & 127;
    xs[row][col] = f2bf(x[m0 * 128 + i]);
  }
  short8 wf[6][4];
#pragma unroll
  for (int kt = 0; kt < 6; ++kt) {
    int row = 96 * w + kt * 16 + c;
#pragma unroll
    for (int kk = 0; kk < 4; ++kk)
      wf[kt][kk] = *(const short8*)&wb[(size_t)row * II + kk * 32 + g * 8];
  }
  LGKM_BARRIER();

  for (int chunk = 0; chunk < 4; ++chunk) {
    short8 bx[4];
#pragma unroll
    for (int kk = 0; kk < 4; ++kk)
      bx[kk] = *(const short8*)&xs[chunk * 16 + c][kk * 32 + g * 8];
    f32x4 acc[6];
#pragma unroll
    for (int kt = 0; kt < 6; ++kt) acc[kt] = (f32x4){0.f, 0.f, 0.f, 0.f};
#pragma unroll
    for (int kt = 0; kt < 6; ++kt)
#pragma unroll
      for (int kk = 0; kk < 4; ++kk)
        acc[kt] = __builtin_amdgcn_mfma_f32_16x16x32_bf16(wf[kt][kk], bx[kk], acc[kt], 0, 0, 0);
#pragma unroll
    for (int kt = 0; kt < 6; ++kt) {
      int gate0 = 96 * w + kt * 16 + g * 4;
      ushort4_t p;
#pragma unroll
      for (int r = 0; r < 4; ++r) p[r] = f2bf(acc[kt][r] + bihs[gate0 + r]);
      *(ushort4_t*)&gst[c][gate0] = p;
    }
    LGKM_BARRIER();
    for (int i = tid; i < 16 * 96; i += 512) {
      int row = i / 96, seg = i - row * 96;
      *(short8*)(gi + (m0 + chunk * 16 + row) * K3 + seg * 8) =
          *(const short8*)&gst[row][seg * 8];
    }
    LGKM_BARRIER();
  }
}

// ---------------- Phase B: recurrence, 16 waves, all-reg weights ----------
// grid 256 (block = batch b), 1024 thr (16 waves). Wave w owns gate rows
// [48w,48w+48) = 3 MFMA tiles; ALL W_hh tiles live in registers (48 tiles x
// 32 VGPR across 16 waves) -> zero weight LDS traffic, 4 waves/SIMD.
// gh redistribution through block-wide scr (padded stride 776), then the
// pointwise runs 1 hidden unit per thread (a=tid>>8, j=tid&255).
// Two lgkm barriers per non-masked step; masked steps: one barrier.
__global__ __launch_bounds__(1024, 4) void rnn_kernel(
    const void* __restrict__ init_raw,
    const float* __restrict__ bhh_g,
    const unsigned short* __restrict__ wsb,  // ws bf16 base: [W_ih | W_hh]
    const unsigned short* __restrict__ gi,
    float* __restrict__ out) {
  __shared__ unsigned short hsb[2][1024];  // h bf16, frag-order, double buf
  __shared__ float scr[4][776];            // gh scratch [agent][row], padded
  __shared__ unsigned char msk[TT];
  __shared__ int detf[3];

  const int tid = threadIdx.x;
  const int b = blockIdx.x;
  const unsigned short* whh_b = wsb + K3 * II;

  if (tid < 3) detf[tid] = 0;
  hsb[0][tid] = 0;
  hsb[1][tid] = 0;

  // ---- is_init layout probe (verified r1-r6 logic; 1024-thread strides) ----
  {
    const unsigned int* wq = (const unsigned int*)init_raw;
    int notf = 0, gt1 = 0, oddnz = 0;
    for (int i = tid; i < (BB * TT / 4); i += 1024) {
      unsigned int v = wq[i];
      notf |= (v != 0u && v != 0x3F800000u);
      gt1 |= (v > 1u);
      if (i & 1) oddnz |= (v != 0u);
    }
    if (notf) atomicOr(&detf[0], 1);
    if (gt1) atomicOr(&detf[1], 1);
    if (oddnz) atomicOr(&detf[2], 1);
  }
  __syncthreads();
  if (tid < TT) {
    int layout = (!detf[0]) ? 1 : (detf[1] ? 0 : (detf[2] ? 1 : 2));
    int e = b * TT + tid;
    unsigned int v;
    if (layout == 0)      v = ((const unsigned char*)init_raw)[e];
    else if (layout == 1) v = ((const unsigned int*)init_raw)[e];
    else                  v = ((const unsigned int*)init_raw)[2 * e];
    msk[tid] = v ? 1 : 0;
  }

  const int l = tid & 63, w = tid >> 6;  // w in [0,16)
  const int c = l & 15, g = l >> 4;
  const bool act = (c < AA);

  // resident W_hh: wave w holds rows [48w, 48w+48) = 3 tiles x 8 k-steps
  short8 wreg[3][8];
#pragma unroll
  for (int s = 0; s < 3; ++s) {
    int row = 48 * w + s * 16 + c;
#pragma unroll
    for (int kk = 0; kk < 8; ++kk)
      wreg[s][kk] = *(const short8*)&whh_b[(size_t)row * HH + kk * 32 + g * 8];
  }

  // pointwise ownership: one (agent a, unit j) per thread
  const int a = tid >> 8, j = tid & 255;
  const float bn = bhh_g[2 * HH + j];

  __syncthreads();

  const unsigned short* gp = gi + ((size_t)(b * TT) * AA + a) * K3 + j;
  float* op = out + ((size_t)(b * TT) * AA + a) * HH + j;
  const int hslot = (j >> 5) * 128 + a * 32 + (j & 31);
  const int hoff = (c & 3) * 32 + g * 8;  // B-frag base (cols 4-15 = dup junk)

  float h = 0.f;
  unsigned short g0A, g1A, g2A, g0B, g1B, g2B;
  int mA, mB;
  const f32x4 Z4 = {0.f, 0.f, 0.f, 0.f};

#define GI_LOAD(S)            \
  do {                        \
    g0##S = gp[0];            \
    g1##S = gp[256];          \
    g2##S = gp[512];          \
    gp += AA * K3;            \
  } while (0)

#define L2E 1.44269504088896f

#define STEP(P, G0, G1, G2, MK)                                                   \
  do {                                                                            \
    float sR, sZ, sN;                                                             \
    if ((MK) != 0) {                                                              \
      h = 0.f; sR = 0.f; sZ = 0.f; sN = 0.f;                                      \
    } else {                                                                      \
      short8 bhf[8];                                                              \
      _Pragma("unroll") for (int kk = 0; kk < 8; ++kk)                            \
          bhf[kk] = *(const short8*)&hsb[P][kk * 128 + hoff];                     \
      f32x4 a0 = __builtin_amdgcn_mfma_f32_16x16x32_bf16(wreg[0][0], bhf[0], Z4, 0, 0, 0); \
      f32x4 a1 = __builtin_amdgcn_mfma_f32_16x16x32_bf16(wreg[1][0], bhf[0], Z4, 0, 0, 0); \
      f32x4 a2 = __builtin_amdgcn_mfma_f32_16x16x32_bf16(wreg[2][0], bhf[0], Z4, 0, 0, 0); \
      _Pragma("unroll") for (int kk = 1; kk < 8; ++kk) {                          \
        a0 = __builtin_amdgcn_mfma_f32_16x16x32_bf16(wreg[0][kk], bhf[kk], a0, 0, 0, 0); \
        a1 = __builtin_amdgcn_mfma_f32_16x16x32_bf16(wreg[1][kk], bhf[kk], a1, 0, 0, 0); \
        a2 = __builtin_amdgcn_mfma_f32_16x16x32_bf16(wreg[2][kk], bhf[kk], a2, 0, 0, 0); \
      }                                                                           \
      if (act) {                                                                  \
        *(f32x4*)&scr[c][48 * w + g * 4] = a0;                                    \
        *(f32x4*)&scr[c][48 * w + 16 + g * 4] = a1;                               \
        *(f32x4*)&scr[c][48 * w + 32 + g * 4] = a2;                               \
      }                                                                           \
      LGKM_BARRIER();                                                             \
      sR = scr[a][j];                                                             \
      sZ = scr[a][256 + j];                                                       \
      sN = scr[a][512 + j];                                                       \
    }                                                                             \
    const float gr = bf2f(G0);                                                    \
    const float gz = bf2f(G1);                                                    \
    const float gn = bf2f(G2);                                                    \
    const float rs = __builtin_amdgcn_rcpf(1.f + __builtin_amdgcn_exp2f(-(gr + sR) * L2E)); \
    const float zs = __builtin_amdgcn_rcpf(1.f + __builtin_amdgcn_exp2f(-(gz + sZ) * L2E)); \
    const float pre = gn + rs * (sN + bn);                                        \
    const float nn = 1.f - 2.f * __builtin_amdgcn_rcpf(1.f + __builtin_amdgcn_exp2f(pre * (2.f * L2E))); \
    h = fmaf(zs, h - nn, nn);                                                     \
    hsb[1 - (P)][hslot] = f2bf(h);                                                \
    *op = h;                                                                      \
    op += AA * HH;                                                                \
    LGKM_BARRIER();                                                               \
  } while (0)

  GI_LOAD(A);  // t = 0
  mA = msk[0];
  for (int t = 0; t < TT - 2; t += 2) {
    GI_LOAD(B);  // t+1
    mB = msk[t + 1];
    STEP(0, g0A, g1A, g2A, mA);
    GI_LOAD(A);  // t+2
    mA = msk[t + 2];
    STEP(1, g0B, g1B, g2B, mB);
  }
  {
    GI_LOAD(B);  // t = 127
    mB = msk[TT - 1];
    STEP(0, g0A, g1A, g2A, mA);
    STEP(1, g0B, g1B, g2B, mB);
  }

  // h_n
  out[(size_t)BB * TT * AA * HH + ((size_t)b * AA + a) * HH + j] = h;
#undef GI_LOAD
#undef STEP
}

// ---------------- Fallback: round-1 kernel (known-pass) ----------------
template <int WSW>
__global__ __launch_bounds__(512, 2) void gru_kernel(
    const float* __restrict__ x,
    const void* __restrict__ init_raw,
    const float* __restrict__ wih_f,
    const float* __restrict__ whh_f,
    const float* __restrict__ bih_g,
    const float* __restrict__ bhh_g,
    const unsigned short* __restrict__ wb,
    float* __restrict__ out) {
  __shared__ alignas(16) unsigned short xs[AA][II + 8];
  __shared__ alignas(16) unsigned short hsb[AA][HH + 8];
  __shared__ float hs32[AA][HH];
  __shared__ float gi_s[K3][5];
  __shared__ float gh_s[K3][5];
  __shared__ float bihs[K3];
  __shared__ float bhhs[K3];
  __shared__ unsigned char msk[TT];
  __shared__ int detf[3];

  const int tid = threadIdx.x;
  const int b = blockIdx.x;

  if (tid < 3) detf[tid] = 0;
  for (int i = tid; i < K3; i += 512) { bihs[i] = bih_g[i]; bhhs[i] = bhh_g[i]; }
  for (int i = tid; i < AA * HH; i += 512) {
    hs32[i >> 8][i & 255] = 0.f;
    hsb[i >> 8][i & 255] = 0;
  }
  __syncthreads();
  {
    const unsigned int* wq = (const unsigned int*)init_raw;
    int notf = 0, gt1 = 0, oddnz = 0;
    for (int i = tid; i < (BB * TT / 4); i += 512) {
      unsigned int v = wq[i];
      notf |= (v != 0u && v != 0x3F800000u);
      gt1 |= (v > 1u);
      if (i & 1) oddnz |= (v != 0u);
    }
    if (notf) atomicOr(&detf[0], 1);
    if (gt1) atomicOr(&detf[1], 1);
    if (oddnz) atomicOr(&detf[2], 1);
  }
  __syncthreads();
  if (tid < TT) {
    int layout = (!detf[0]) ? 1 : (detf[1] ? 0 : (detf[2] ? 1 : 2));
    int e = b * TT + tid;
    unsigned int v;
    if (layout == 0)      v = ((const unsigned char*)init_raw)[e];
    else if (layout == 1) v = ((const unsigned int*)init_raw)[e];
    else                  v = ((const unsigned int*)init_raw)[2 * e];
    msk[tid] = v ? 1 : 0;
  }
  __syncthreads();

  const int l = tid & 63;
  const int w = tid >> 6;
  const int c = l & 15;
  const int g = l >> 4;
  const bool act = (c < AA);
  const int xa = tid >> 7, xi = tid & 127;
  const float* xrow = x + (size_t)b * TT * AA * II;
  const unsigned short* wihb = wb;
  const unsigned short* whhb = wb + K3 * II;

  for (int t = 0; t < TT; ++t) {
    xs[xa][xi] = f2bf(xrow[(size_t)t * (AA * II) + tid]);
    if (msk[t]) {
      for (int i = tid; i < AA * HH; i += 512) {
        hs32[i >> 8][i & 255] = 0.f;
        hsb[i >> 8][i & 255] = 0;
      }
    }
    __syncthreads();

    short8 bx[4], bh[8];
    if (act) {
#pragma unroll
      for (int kk = 0; kk < 4; ++kk) bx[kk] = *(const short8*)&xs[c][kk * 32 + g * 8];
#pragma unroll
      for (int kk = 0; kk < 8; ++kk) bh[kk] = *(const short8*)&hsb[c][kk * 32 + g * 8];
    } else {
#pragma unroll
      for (int kk = 0; kk < 4; ++kk) bx[kk] = (short8)0;
#pragma unroll
      for (int kk = 0; kk < 8; ++kk) bh[kk] = (short8)0;
    }

#pragma unroll
    for (int kt = 0; kt < 6; ++kt) {
      const int ar = w * 96 + kt * 16 + c;
      f32x4 acc = {0.f, 0.f, 0.f, 0.f};
#pragma unroll
      for (int kk = 0; kk < 4; ++kk) {
        short8 aw;
        if (WSW) {
          aw = *(const short8*)&wihb[(size_t)ar * II + kk * 32 + g * 8];
        } else {
          const float* p = &wih_f[(size_t)ar * II + kk * 32 + g * 8];
#pragma unroll
          for (int e = 0; e < 8; ++e) aw[e] = (short)f2bf(p[e]);
        }
        acc = __builtin_amdgcn_mfma_f32_16x16x32_bf16(aw, bx[kk], acc, 0, 0, 0);
      }
      if (act) {
        const int dr = w * 96 + kt * 16 + g * 4;
#pragma unroll
        for (int r = 0; r < 4; ++r) gi_s[dr + r][c] = acc[r];
      }
    }

#pragma unroll
    for (int kt = 0; kt < 6; ++kt) {
      const int ar = w * 96 + kt * 16 + c;
      f32x4 acc = {0.f, 0.f, 0.f, 0.f};
#pragma unroll
      for (int kk = 0; kk < 8; ++kk) {
        short8 aw;
        if (WSW) {
          aw = *(const short8*)&whhb[(size_t)ar * HH + kk * 32 + g * 8];
        } else {
          const float* p = &whh_f[(size_t)ar * HH + kk * 32 + g * 8];
#pragma unroll
          for (int e = 0; e < 8; ++e) aw[e] = (short)f2bf(p[e]);
        }
        acc = __builtin_amdgcn_mfma_f32_16x16x32_bf16(aw, bh[kk], acc, 0, 0, 0);
      }
      if (act) {
        const int dr = w * 96 + kt * 16 + g * 4;
#pragma unroll
        for (int r = 0; r < 4; ++r) gh_s[dr + r][c] = acc[r];
      }
    }
    __syncthreads();

#pragma unroll
    for (int it = 0; it < 2; ++it) {
      const int idx = it * 512 + tid;
      const int a = idx >> 8, j = idx & 255;
      const float ir = gi_s[j][a] + bihs[j];
      const float iz = gi_s[HH + j][a] + bihs[HH + j];
      const float inn = gi_s[2 * HH + j][a] + bihs[2 * HH + j];
      const float hr = gh_s[j][a] + bhhs[j];
      const float hz = gh_s[HH + j][a] + bhhs[HH + j];
      const float hn = gh_s[2 * HH + j][a] + bhhs[2 * HH + j];
      const float r = 1.f / (1.f + __expf(-(ir + hr)));
      const float z = 1.f / (1.f + __expf(-(iz + hz)));
      const float pre = inn + r * hn;
      const float ea = __expf(-2.f * fabsf(pre));
      float n = (1.f - ea) / (1.f + ea);
      n = (pre < 0.f) ? -n : n;
      const float hold = hs32[a][j];
      const float hnew = (1.f - z) * n + z * hold;
      hs32[a][j] = hnew;
      hsb[a][j] = f2bf(hnew);
      out[(((size_t)b * TT + t) * AA + a) * HH + j] = hnew;
      if (t == TT - 1)
        out[(size_t)BB * TT * AA * HH + ((size_t)b * AA + a) * HH + j] = hnew;
    }
    __syncthreads();
  }
}

extern "C" void kernel_launch(void* const* d_in, const int* in_sizes, int n_in,
                              void* d_out, int out_size, void* d_ws, size_t ws_size,
                              hipStream_t stream) {
  (void)in_sizes; (void)n_in; (void)out_size;
  const float* x = (const float*)d_in[0];
  const void* is_init = d_in[1];
  const float* wih = (const float*)d_in[2];
  const float* whh = (const float*)d_in[3];
  const float* bih = (const float*)d_in[4];
  const float* bhh = (const float*)d_in[5];
  float* out = (float*)d_out;

  const size_t W_ELS = (size_t)(K3 * II + K3 * HH);        // 294,912
  const size_t W_BYTES = W_ELS * 2;                        // 589,824
  const size_t GI_BYTES = (size_t)BB * TT * AA * K3 * 2;   // 201,326,592

  if (ws_size >= W_BYTES + GI_BYTES) {
    unsigned short* wb = (unsigned short*)d_ws;
    unsigned short* gi = wb + W_ELS;
    wconv_kernel<<<(int)(W_ELS / 512), 512, 0, stream>>>(wih, whh, wb);
    gi_kernel<<<2048, 512, 0, stream>>>(x, bih, bhh, wb, gi);
    rnn_kernel<<<BB, 1024, 0, stream>>>(is_init, bhh, wb, gi, out);
    return;
  }
  // fallback (round-1 verified path)
  if (ws_size >= W_BYTES) {
    unsigned short* wb = (unsigned short*)d_ws;
    wconv_kernel<<<(int)(W_ELS / 512), 512, 0, stream>>>(wih, whh, wb);
    gru_kernel<1><<<BB, 512, 0, stream>>>(x, is_init, wih, whh, bih, bhh, wb, out);
  } else {
    gru_kernel<0><<<BB, 512, 0, stream>>>(x, is_init, wih, whh, bih, bhh, nullptr, out);
  }
}

// Round 8
// 323.467 us; speedup vs baseline: 1.1144x; 1.1144x over previous
//
#include <hip/hip_runtime.h>
#include <cstdint>
#include <cstddef>

#define BB 256
#define TT 128
#define AA 4
#define II 128
#define HH 256
#define K3 768  // 3*H

typedef __attribute__((ext_vector_type(8))) short short8;
typedef __attribute__((ext_vector_type(4))) float f32x4;
typedef __attribute__((ext_vector_type(4))) unsigned short ushort4_t;

// workgroup barrier draining ONLY lgkmcnt (LDS), not vmcnt.
#define LGKM_BARRIER() asm volatile("s_waitcnt lgkmcnt(0)\n\ts_barrier" ::: "memory")

static __device__ __forceinline__ unsigned short f2bf(float f) {
  unsigned int b = __float_as_uint(f);
  return (unsigned short)((b + 0x7FFFu + ((b >> 16) & 1u)) >> 16);  // RNE
}
static __device__ __forceinline__ float bf2f(unsigned short u) {
  return __uint_as_float(((unsigned int)u) << 16);
}

// fp32 -> bf16 weight conversion (FALLBACK PATH ONLY)
__global__ void wconv_kernel(const float* __restrict__ wih,
                             const float* __restrict__ whh,
                             unsigned short* __restrict__ o) {
  int i = blockIdx.x * 512 + threadIdx.x;
  float v = (i < K3 * II) ? wih[i] : whh[i - K3 * II];
  o[i] = f2bf(v);
}

// ---------------- Phase A: gi = x * W_ih^T + b_ih (+ b_hh for r,z), bf16 ----
// W_ih converted inline from fp32 (L2-resident) — no wconv pre-pass.
__global__ __launch_bounds__(512, 2) void gi_kernel(
    const float* __restrict__ x,
    const float* __restrict__ bih_g,
    const float* __restrict__ bhh_g,
    const float* __restrict__ wih_f,
    unsigned short* __restrict__ gi) {
  __shared__ alignas(16) unsigned short xs[64][144];
  __shared__ alignas(16) unsigned short gst[16][792];
  __shared__ float bihs[K3];

  const int tid = threadIdx.x;
  const int l = tid & 63, w = tid >> 6;
  const int c = l & 15, g = l >> 4;
  const size_t m0 = (size_t)blockIdx.x * 64;

  for (int i = tid; i < K3; i += 512)
    bihs[i] = bih_g[i] + (i < 2 * HH ? bhh_g[i] : 0.f);
  for (int i = tid; i < 64 * 128; i += 512) {
    int row = i >> 7, col = i & 127;
    xs[row][col] = f2bf(x[m0 * 128 + i]);
  }
  short8 wf[6][4];
#pragma unroll
  for (int kt = 0; kt < 6; ++kt) {
    int row = 96 * w + kt * 16 + c;
#pragma unroll
    for (int kk = 0; kk < 4; ++kk) {
      const float* p = &wih_f[(size_t)row * II + kk * 32 + g * 8];
#pragma unroll
      for (int e = 0; e < 8; ++e) wf[kt][kk][e] = (short)f2bf(p[e]);
    }
  }
  LGKM_BARRIER();

  for (int chunk = 0; chunk < 4; ++chunk) {
    short8 bx[4];
#pragma unroll
    for (int kk = 0; kk < 4; ++kk)
      bx[kk] = *(const short8*)&xs[chunk * 16 + c][kk * 32 + g * 8];
    f32x4 acc[6];
#pragma unroll
    for (int kt = 0; kt < 6; ++kt) acc[kt] = (f32x4){0.f, 0.f, 0.f, 0.f};
#pragma unroll
    for (int kt = 0; kt < 6; ++kt)
#pragma unroll
      for (int kk = 0; kk < 4; ++kk)
        acc[kt] = __builtin_amdgcn_mfma_f32_16x16x32_bf16(wf[kt][kk], bx[kk], acc[kt], 0, 0, 0);
#pragma unroll
    for (int kt = 0; kt < 6; ++kt) {
      int gate0 = 96 * w + kt * 16 + g * 4;
      ushort4_t p;
#pragma unroll
      for (int r = 0; r < 4; ++r) p[r] = f2bf(acc[kt][r] + bihs[gate0 + r]);
      *(ushort4_t*)&gst[c][gate0] = p;
    }
    LGKM_BARRIER();
    for (int i = tid; i < 16 * 96; i += 512) {
      int row = i / 96, seg = i - row * 96;
      *(short8*)(gi + (m0 + chunk * 16 + row) * K3 + seg * 8) =
          *(const short8*)&gst[row][seg * 8];
    }
    LGKM_BARRIER();
  }
}

// ---------------- Phase B: recurrence, gate-aligned rows ----------------
// 8 waves, grid 256. Wave w owns units [32w,32w+32) across ALL 3 gates:
// tiles R0,R1,Z0,Z1,N0 in registers (160 regs, AGPR-eligible), N1 in LDS
// (8 ds_read_b128/step — half of r6). D-frags hold all gates for the wave's
// 128 (agent,unit) pairs -> scr stays WAVE-LOCAL, one barrier/step.
// Pointwise: 2 units/thread, all 64 lanes. Weights converted inline (fp32).
__global__ __launch_bounds__(512, 2) void rnn_kernel(
    const void* __restrict__ init_raw,
    const float* __restrict__ bhh_g,
    const float* __restrict__ whh_f,
    const unsigned short* __restrict__ gi,
    float* __restrict__ out) {
  extern __shared__ char smem[];
  unsigned short* wlN1 = (unsigned short*)smem;            // 65536 B (N1 frags)
  unsigned short* hsb = (unsigned short*)(smem + 65536);   // 2 x 1024 ushorts
  float* scr = (float*)(smem + 69632);                     // 8 x 480 floats
  unsigned char* msk = (unsigned char*)(smem + 84992);     // 128 B
  int* detf = (int*)(smem + 85120);                        // 12 B

  const int tid = threadIdx.x;
  const int b = blockIdx.x;

  if (tid < 3) detf[tid] = 0;
  for (int i = tid; i < 2048; i += 512) hsb[i] = 0;
  // N1 tiles (rows 512+32w+16..+32) -> LDS fragment order, cvt from fp32
  for (int e = tid; e < 4096; e += 512) {
    int w2 = e >> 9, kk = (e >> 6) & 7, l2 = e & 63;
    int row = 512 + 32 * w2 + 16 + (l2 & 15);
    int col = kk * 32 + (l2 >> 4) * 8;
    const float* p = whh_f + (size_t)row * HH + col;
    short8 v;
#pragma unroll
    for (int q = 0; q < 8; ++q) v[q] = (short)f2bf(p[q]);
    *(short8*)(wlN1 + e * 8) = v;
  }

  // ---- is_init layout probe (verified r1-r6 logic) ----
  {
    const unsigned int* wq = (const unsigned int*)init_raw;
    int notf = 0, gt1 = 0, oddnz = 0;
    for (int i = tid; i < (BB * TT / 4); i += 512) {
      unsigned int v = wq[i];
      notf |= (v != 0u && v != 0x3F800000u);
      gt1 |= (v > 1u);
      if (i & 1) oddnz |= (v != 0u);
    }
    if (notf) atomicOr(&detf[0], 1);
    if (gt1) atomicOr(&detf[1], 1);
    if (oddnz) atomicOr(&detf[2], 1);
  }
  __syncthreads();
  if (tid < TT) {
    int layout = (!detf[0]) ? 1 : (detf[1] ? 0 : (detf[2] ? 1 : 2));
    int e = b * TT + tid;
    unsigned int v;
    if (layout == 0)      v = ((const unsigned char*)init_raw)[e];
    else if (layout == 1) v = ((const unsigned int*)init_raw)[e];
    else                  v = ((const unsigned int*)init_raw)[2 * e];
    msk[tid] = v ? 1 : 0;
  }

  const int l = tid & 63, w = tid >> 6;
  const int c = l & 15, g = l >> 4;
  const bool act = (c < AA);

  // 5 register tiles: R0,R1,Z0,Z1,N0 (gate-aligned, units [32w,32w+32))
  short8 wreg[5][8];
  {
    const int rb0 = 32 * w + c;
    const int rowb[5] = {rb0, rb0 + 16, 256 + rb0, 256 + rb0 + 16, 512 + rb0};
#pragma unroll
    for (int q = 0; q < 5; ++q)
#pragma unroll
      for (int kk = 0; kk < 8; ++kk) {
        const float* p = whh_f + (size_t)rowb[q] * HH + kk * 32 + g * 8;
#pragma unroll
        for (int e = 0; e < 8; ++e) wreg[q][kk][e] = (short)f2bf(p[e]);
      }
  }

  // pointwise mapping: agent a = g, units j0 = 32w + 2c, j0+1
  const int a = g;
  const int u2 = 2 * c;
  const int j0 = 32 * w + u2;
  const float2 bn2 = *(const float2*)&bhh_g[2 * HH + j0];

  __syncthreads();

  const unsigned short* gp = gi + ((size_t)(b * TT) * AA + a) * K3 + j0;
  float* op = out + ((size_t)(b * TT) * AA + a) * HH + j0;
  const unsigned short* hrd = hsb + ((c & 3) * 4 + g) * 8;   // + P*1024 + kk*128
  unsigned short* hwp = hsb + w * 128 + a * 32 + u2;         // + (1-P)*1024
  float* swp = scr + w * 480 + c * 40 + g * 4;               // + {0,16,160,176,320,336}
  const float* srp = scr + w * 480 + a * 40 + u2;            // + gt*160
  const unsigned short* wlp = wlN1 + w * 4096 + l * 8;       // + kk*512

  float h0 = 0.f, h1 = 0.f;
  unsigned int gcA[3], gcB[3];
  int mA, mB;
  const f32x4 Z4 = {0.f, 0.f, 0.f, 0.f};

#define GI_LOAD(GC)                               \
  do {                                            \
    GC[0] = *(const unsigned int*)(gp);           \
    GC[1] = *(const unsigned int*)(gp + 256);     \
    GC[2] = *(const unsigned int*)(gp + 512);     \
    gp += AA * K3;                                \
  } while (0)

#define L2E 1.44269504088896f

#define STEP(P, GC, MK)                                                           \
  do {                                                                            \
    float sR0, sR1, sZ0, sZ1, sN0, sN1;                                           \
    if ((MK) != 0) {                                                              \
      h0 = 0.f; h1 = 0.f;                                                         \
      sR0 = sR1 = sZ0 = sZ1 = sN0 = sN1 = 0.f;                                    \
    } else {                                                                      \
      short8 bhf[8];                                                              \
      _Pragma("unroll") for (int kk = 0; kk < 8; ++kk)                            \
          bhf[kk] = *(const short8*)(hrd + (P) * 1024 + kk * 128);                \
      f32x4 aR0 = __builtin_amdgcn_mfma_f32_16x16x32_bf16(wreg[0][0], bhf[0], Z4, 0, 0, 0); \
      f32x4 aR1 = __builtin_amdgcn_mfma_f32_16x16x32_bf16(wreg[1][0], bhf[0], Z4, 0, 0, 0); \
      f32x4 aZ0 = __builtin_amdgcn_mfma_f32_16x16x32_bf16(wreg[2][0], bhf[0], Z4, 0, 0, 0); \
      f32x4 aZ1 = __builtin_amdgcn_mfma_f32_16x16x32_bf16(wreg[3][0], bhf[0], Z4, 0, 0, 0); \
      f32x4 aN0 = __builtin_amdgcn_mfma_f32_16x16x32_bf16(wreg[4][0], bhf[0], Z4, 0, 0, 0); \
      f32x4 aN1 = __builtin_amdgcn_mfma_f32_16x16x32_bf16(                        \
          *(const short8*)(wlp), bhf[0], Z4, 0, 0, 0);                            \
      _Pragma("unroll") for (int kk = 1; kk < 8; ++kk) {                          \
        aR0 = __builtin_amdgcn_mfma_f32_16x16x32_bf16(wreg[0][kk], bhf[kk], aR0, 0, 0, 0); \
        aR1 = __builtin_amdgcn_mfma_f32_16x16x32_bf16(wreg[1][kk], bhf[kk], aR1, 0, 0, 0); \
        aZ0 = __builtin_amdgcn_mfma_f32_16x16x32_bf16(wreg[2][kk], bhf[kk], aZ0, 0, 0, 0); \
        aZ1 = __builtin_amdgcn_mfma_f32_16x16x32_bf16(wreg[3][kk], bhf[kk], aZ1, 0, 0, 0); \
        aN0 = __builtin_amdgcn_mfma_f32_16x16x32_bf16(wreg[4][kk], bhf[kk], aN0, 0, 0, 0); \
        aN1 = __builtin_amdgcn_mfma_f32_16x16x32_bf16(                            \
            *(const short8*)(wlp + kk * 512), bhf[kk], aN1, 0, 0, 0);             \
      }                                                                           \
      if (act) {                                                                  \
        *(f32x4*)(swp + 0)   = aR0;                                               \
        *(f32x4*)(swp + 16)  = aR1;                                               \
        *(f32x4*)(swp + 160) = aZ0;                                               \
        *(f32x4*)(swp + 176) = aZ1;                                               \
        *(f32x4*)(swp + 320) = aN0;                                               \
        *(f32x4*)(swp + 336) = aN1;                                               \
      }                                                                           \
      float2 vR = *(const float2*)(srp);                                          \
      float2 vZ = *(const float2*)(srp + 160);                                    \
      float2 vN = *(const float2*)(srp + 320);                                    \
      sR0 = vR.x; sR1 = vR.y; sZ0 = vZ.x; sZ1 = vZ.y; sN0 = vN.x; sN1 = vN.y;     \
    }                                                                             \
    const float gr0 = bf2f((unsigned short)(GC[0]));                              \
    const float gr1 = bf2f((unsigned short)(GC[0] >> 16));                        \
    const float gz0 = bf2f((unsigned short)(GC[1]));                              \
    const float gz1 = bf2f((unsigned short)(GC[1] >> 16));                        \
    const float gn0 = bf2f((unsigned short)(GC[2]));                              \
    const float gn1 = bf2f((unsigned short)(GC[2] >> 16));                        \
    const float rs0 = __builtin_amdgcn_rcpf(1.f + __builtin_amdgcn_exp2f(-(gr0 + sR0) * L2E)); \
    const float rs1 = __builtin_amdgcn_rcpf(1.f + __builtin_amdgcn_exp2f(-(gr1 + sR1) * L2E)); \
    const float zs0 = __builtin_amdgcn_rcpf(1.f + __builtin_amdgcn_exp2f(-(gz0 + sZ0) * L2E)); \
    const float zs1 = __builtin_amdgcn_rcpf(1.f + __builtin_amdgcn_exp2f(-(gz1 + sZ1) * L2E)); \
    const float pre0 = gn0 + rs0 * (sN0 + bn2.x);                                 \
    const float pre1 = gn1 + rs1 * (sN1 + bn2.y);                                 \
    const float nn0 = 1.f - 2.f * __builtin_amdgcn_rcpf(1.f + __builtin_amdgcn_exp2f(pre0 * (2.f * L2E))); \
    const float nn1 = 1.f - 2.f * __builtin_amdgcn_rcpf(1.f + __builtin_amdgcn_exp2f(pre1 * (2.f * L2E))); \
    h0 = fmaf(zs0, h0 - nn0, nn0);                                                \
    h1 = fmaf(zs1, h1 - nn1, nn1);                                                \
    unsigned int hw = (unsigned int)f2bf(h0) | ((unsigned int)f2bf(h1) << 16);    \
    *(unsigned int*)(hwp + (1 - (P)) * 1024) = hw;                                \
    float2 o2; o2.x = h0; o2.y = h1;                                              \
    *(float2*)op = o2;                                                            \
    op += AA * HH;                                                                \
    LGKM_BARRIER();                                                               \
  } while (0)

  GI_LOAD(gcA);  // t = 0
  mA = msk[0];
  for (int t = 0; t < TT - 2; t += 2) {
    GI_LOAD(gcB);  // t+1
    mB = msk[t + 1];
    STEP(0, gcA, mA);
    GI_LOAD(gcA);  // t+2
    mA = msk[t + 2];
    STEP(1, gcB, mB);
  }
  {
    GI_LOAD(gcB);  // t = 127
    mB = msk[TT - 1];
    STEP(0, gcA, mA);
    STEP(1, gcB, mB);
  }

  {
    float* hp = out + (size_t)BB * TT * AA * HH + ((size_t)b * AA + a) * HH + j0;
    float2 o2; o2.x = h0; o2.y = h1;
    *(float2*)hp = o2;
  }
#undef GI_LOAD
#undef STEP
}

// ---------------- Fallback: round-1 kernel (known-pass) ----------------
template <int WSW>
__global__ __launch_bounds__(512, 2) void gru_kernel(
    const float* __restrict__ x,
    const void* __restrict__ init_raw,
    const float* __restrict__ wih_f,
    const float* __restrict__ whh_f,
    const float* __restrict__ bih_g,
    const float* __restrict__ bhh_g,
    const unsigned short* __restrict__ wb,
    float* __restrict__ out) {
  __shared__ alignas(16) unsigned short xs[AA][II + 8];
  __shared__ alignas(16) unsigned short hsb[AA][HH + 8];
  __shared__ float hs32[AA][HH];
  __shared__ float gi_s[K3][5];
  __shared__ float gh_s[K3][5];
  __shared__ float bihs[K3];
  __shared__ float bhhs[K3];
  __shared__ unsigned char msk[TT];
  __shared__ int detf[3];

  const int tid = threadIdx.x;
  const int b = blockIdx.x;

  if (tid < 3) detf[tid] = 0;
  for (int i = tid; i < K3; i += 512) { bihs[i] = bih_g[i]; bhhs[i] = bhh_g[i]; }
  for (int i = tid; i < AA * HH; i += 512) {
    hs32[i >> 8][i & 255] = 0.f;
    hsb[i >> 8][i & 255] = 0;
  }
  __syncthreads();
  {
    const unsigned int* wq = (const unsigned int*)init_raw;
    int notf = 0, gt1 = 0, oddnz = 0;
    for (int i = tid; i < (BB * TT / 4); i += 512) {
      unsigned int v = wq[i];
      notf |= (v != 0u && v != 0x3F800000u);
      gt1 |= (v > 1u);
      if (i & 1) oddnz |= (v != 0u);
    }
    if (notf) atomicOr(&detf[0], 1);
    if (gt1) atomicOr(&detf[1], 1);
    if (oddnz) atomicOr(&detf[2], 1);
  }
  __syncthreads();
  if (tid < TT) {
    int layout = (!detf[0]) ? 1 : (detf[1] ? 0 : (detf[2] ? 1 : 2));
    int e = b * TT + tid;
    unsigned int v;
    if (layout == 0)      v = ((const unsigned char*)init_raw)[e];
    else if (layout == 1) v = ((const unsigned int*)init_raw)[e];
    else                  v = ((const unsigned int*)init_raw)[2 * e];
    msk[tid] = v ? 1 : 0;
  }
  __syncthreads();

  const int l = tid & 63;
  const int w = tid >> 6;
  const int c = l & 15;
  const int g = l >> 4;
  const bool act = (c < AA);
  const int xa = tid >> 7, xi = tid & 127;
  const float* xrow = x + (size_t)b * TT * AA * II;
  const unsigned short* wihb = wb;
  const unsigned short* whhb = wb + K3 * II;

  for (int t = 0; t < TT; ++t) {
    xs[xa][xi] = f2bf(xrow[(size_t)t * (AA * II) + tid]);
    if (msk[t]) {
      for (int i = tid; i < AA * HH; i += 512) {
        hs32[i >> 8][i & 255] = 0.f;
        hsb[i >> 8][i & 255] = 0;
      }
    }
    __syncthreads();

    short8 bx[4], bh[8];
    if (act) {
#pragma unroll
      for (int kk = 0; kk < 4; ++kk) bx[kk] = *(const short8*)&xs[c][kk * 32 + g * 8];
#pragma unroll
      for (int kk = 0; kk < 8; ++kk) bh[kk] = *(const short8*)&hsb[c][kk * 32 + g * 8];
    } else {
#pragma unroll
      for (int kk = 0; kk < 4; ++kk) bx[kk] = (short8)0;
#pragma unroll
      for (int kk = 0; kk < 8; ++kk) bh[kk] = (short8)0;
    }

#pragma unroll
    for (int kt = 0; kt < 6; ++kt) {
      const int ar = w * 96 + kt * 16 + c;
      f32x4 acc = {0.f, 0.f, 0.f, 0.f};
#pragma unroll
      for (int kk = 0; kk < 4; ++kk) {
        short8 aw;
        if (WSW) {
          aw = *(const short8*)&wihb[(size_t)ar * II + kk * 32 + g * 8];
        } else {
          const float* p = &wih_f[(size_t)ar * II + kk * 32 + g * 8];
#pragma unroll
          for (int e = 0; e < 8; ++e) aw[e] = (short)f2bf(p[e]);
        }
        acc = __builtin_amdgcn_mfma_f32_16x16x32_bf16(aw, bx[kk], acc, 0, 0, 0);
      }
      if (act) {
        const int dr = w * 96 + kt * 16 + g * 4;
#pragma unroll
        for (int r = 0; r < 4; ++r) gi_s[dr + r][c] = acc[r];
      }
    }

#pragma unroll
    for (int kt = 0; kt < 6; ++kt) {
      const int ar = w * 96 + kt * 16 + c;
      f32x4 acc = {0.f, 0.f, 0.f, 0.f};
#pragma unroll
      for (int kk = 0; kk < 8; ++kk) {
        short8 aw;
        if (WSW) {
          aw = *(const short8*)&whhb[(size_t)ar * HH + kk * 32 + g * 8];
        } else {
          const float* p = &whh_f[(size_t)ar * HH + kk * 32 + g * 8];
#pragma unroll
          for (int e = 0; e < 8; ++e) aw[e] = (short)f2bf(p[e]);
        }
        acc = __builtin_amdgcn_mfma_f32_16x16x32_bf16(aw, bh[kk], acc, 0, 0, 0);
      }
      if (act) {
        const int dr = w * 96 + kt * 16 + g * 4;
#pragma unroll
        for (int r = 0; r < 4; ++r) gh_s[dr + r][c] = acc[r];
      }
    }
    __syncthreads();

#pragma unroll
    for (int it = 0; it < 2; ++it) {
      const int idx = it * 512 + tid;
      const int a = idx >> 8, j = idx & 255;
      const float ir = gi_s[j][a] + bihs[j];
      const float iz = gi_s[HH + j][a] + bihs[HH + j];
      const float inn = gi_s[2 * HH + j][a] + bihs[2 * HH + j];
      const float hr = gh_s[j][a] + bhhs[j];
      const float hz = gh_s[HH + j][a] + bhhs[HH + j];
      const float hn = gh_s[2 * HH + j][a] + bhhs[2 * HH + j];
      const float r = 1.f / (1.f + __expf(-(ir + hr)));
      const float z = 1.f / (1.f + __expf(-(iz + hz)));
      const float pre = inn + r * hn;
      const float ea = __expf(-2.f * fabsf(pre));
      float n = (1.f - ea) / (1.f + ea);
      n = (pre < 0.f) ? -n : n;
      const float hold = hs32[a][j];
      const float hnew = (1.f - z) * n + z * hold;
      hs32[a][j] = hnew;
      hsb[a][j] = f2bf(hnew);
      out[(((size_t)b * TT + t) * AA + a) * HH + j] = hnew;
      if (t == TT - 1)
        out[(size_t)BB * TT * AA * HH + ((size_t)b * AA + a) * HH + j] = hnew;
    }
    __syncthreads();
  }
}

extern "C" void kernel_launch(void* const* d_in, const int* in_sizes, int n_in,
                              void* d_out, int out_size, void* d_ws, size_t ws_size,
                              hipStream_t stream) {
  (void)in_sizes; (void)n_in; (void)out_size;
  const float* x = (const float*)d_in[0];
  const void* is_init = d_in[1];
  const float* wih = (const float*)d_in[2];
  const float* whh = (const float*)d_in[3];
  const float* bih = (const float*)d_in[4];
  const float* bhh = (const float*)d_in[5];
  float* out = (float*)d_out;

  const size_t W_ELS = (size_t)(K3 * II + K3 * HH);        // 294,912
  const size_t W_BYTES = W_ELS * 2;                        // 589,824
  const size_t GI_BYTES = (size_t)BB * TT * AA * K3 * 2;   // 201,326,592
  const int SMEM = 85136;

  if (ws_size >= GI_BYTES) {
    hipError_t e = hipFuncSetAttribute(
        (const void*)rnn_kernel, hipFuncAttributeMaxDynamicSharedMemorySize, SMEM);
    if (e == hipSuccess) {
      unsigned short* gi = (unsigned short*)d_ws;
      gi_kernel<<<2048, 512, 0, stream>>>(x, bih, bhh, wih, gi);
      rnn_kernel<<<BB, 512, SMEM, stream>>>(is_init, bhh, whh, gi, out);
      return;
    }
  }
  // fallback (round-1 verified path)
  if (ws_size >= W_BYTES) {
    unsigned short* wb = (unsigned short*)d_ws;
    wconv_kernel<<<(int)(W_ELS / 512), 512, 0, stream>>>(wih, whh, wb);
    gru_kernel<1><<<BB, 512, 0, stream>>>(x, is_init, wih, whh, bih, bhh, wb, out);
  } else {
    gru_kernel<0><<<BB, 512, 0, stream>>>(x, is_init, wih, whh, bih, bhh, nullptr, out);
  }
}

// Round 9
// 243.808 us; speedup vs baseline: 1.4784x; 1.3267x over previous
//
#include <hip/hip_runtime.h>
#include <cstdint>
#include <cstddef>

#define BB 256
#define TT 128
#define AA 4
#define II 128
#define HH 256
#define K3 768  // 3*H

typedef __attribute__((ext_vector_type(8))) short short8;
typedef __attribute__((ext_vector_type(4))) float f32x4;
typedef __attribute__((ext_vector_type(4))) unsigned short ushort4_t;

// workgroup barrier draining ONLY lgkmcnt (LDS), not vmcnt.
#define LGKM_BARRIER() asm volatile("s_waitcnt lgkmcnt(0)\n\ts_barrier" ::: "memory")

static __device__ __forceinline__ unsigned short f2bf(float f) {
  unsigned int b = __float_as_uint(f);
  return (unsigned short)((b + 0x7FFFu + ((b >> 16) & 1u)) >> 16);  // RNE
}
static __device__ __forceinline__ float bf2f(unsigned short u) {
  return __uint_as_float(((unsigned int)u) << 16);
}

// fp32 -> bf16 weight conversion into workspace (W_ih then W_hh, row-major)
__global__ void wconv_kernel(const float* __restrict__ wih,
                             const float* __restrict__ whh,
                             unsigned short* __restrict__ o) {
  int i = blockIdx.x * 512 + threadIdx.x;
  float v = (i < K3 * II) ? wih[i] : whh[i - K3 * II];
  o[i] = f2bf(v);
}

// ---------------- Phase A: gi = x * W_ih^T + b_ih (+ b_hh for r,z), bf16 ----
__global__ __launch_bounds__(512, 2) void gi_kernel(
    const float* __restrict__ x,
    const float* __restrict__ bih_g,
    const float* __restrict__ bhh_g,
    const unsigned short* __restrict__ wb,   // W_ih bf16 at ws[0]
    unsigned short* __restrict__ gi) {
  __shared__ alignas(16) unsigned short xs[64][144];
  __shared__ alignas(16) unsigned short gst[16][792];
  __shared__ float bihs[K3];

  const int tid = threadIdx.x;
  const int l = tid & 63, w = tid >> 6;
  const int c = l & 15, g = l >> 4;
  const size_t m0 = (size_t)blockIdx.x * 64;

  for (int i = tid; i < K3; i += 512)
    bihs[i] = bih_g[i] + (i < 2 * HH ? bhh_g[i] : 0.f);
  for (int i = tid; i < 64 * 128; i += 512) {
    int row = i >> 7, col = i & 127;
    xs[row][col] = f2bf(x[m0 * 128 + i]);
  }
  short8 wf[6][4];
#pragma unroll
  for (int kt = 0; kt < 6; ++kt) {
    int row = 96 * w + kt * 16 + c;
#pragma unroll
    for (int kk = 0; kk < 4; ++kk)
      wf[kt][kk] = *(const short8*)&wb[(size_t)row * II + kk * 32 + g * 8];
  }
  LGKM_BARRIER();

  for (int chunk = 0; chunk < 4; ++chunk) {
    short8 bx[4];
#pragma unroll
    for (int kk = 0; kk < 4; ++kk)
      bx[kk] = *(const short8*)&xs[chunk * 16 + c][kk * 32 + g * 8];
    f32x4 acc[6];
#pragma unroll
    for (int kt = 0; kt < 6; ++kt) acc[kt] = (f32x4){0.f, 0.f, 0.f, 0.f};
#pragma unroll
    for (int kt = 0; kt < 6; ++kt)
#pragma unroll
      for (int kk = 0; kk < 4; ++kk)
        acc[kt] = __builtin_amdgcn_mfma_f32_16x16x32_bf16(wf[kt][kk], bx[kk], acc[kt], 0, 0, 0);
#pragma unroll
    for (int kt = 0; kt < 6; ++kt) {
      int gate0 = 96 * w + kt * 16 + g * 4;
      ushort4_t p;
#pragma unroll
      for (int r = 0; r < 4; ++r) p[r] = f2bf(acc[kt][r] + bihs[gate0 + r]);
      *(ushort4_t*)&gst[c][gate0] = p;
    }
    LGKM_BARRIER();
    for (int i = tid; i < 16 * 96; i += 512) {
      int row = i / 96, seg = i - row * 96;
      *(short8*)(gi + (m0 + chunk * 16 + row) * K3 + seg * 8) =
          *(const short8*)&gst[row][seg * 8];
    }
    LGKM_BARRIER();
  }
}

// ---------------- Phase B: recurrence, gate-aligned, 1 barrier/step --------
// 8 waves, grid 256 (block = batch). Wave w owns units [32w,32w+32) of ALL
// 3 gates: R0,R1,Z0,Z1 tiles in registers (128 AGPR — r6-proven budget,
// short8 loads from bf16 ws), N0,N1 from LDS frag-order (16 ds_read_b128).
// D-frags are wave-local for all the wave's (agent,unit) pairs -> scr
// redistribution needs NO barrier (wave-internal lgkmcnt only); the single
// end-of-step barrier orders the hsb double-buffer hand-off.
// Pointwise: 2 units/thread, all 64 lanes (a=g, j0=32w+2c).
__global__ __launch_bounds__(512, 2) void rnn_kernel(
    const void* __restrict__ init_raw,
    const float* __restrict__ bhh_g,
    const unsigned short* __restrict__ wsb,  // ws bf16 base: [W_ih | W_hh]
    const unsigned short* __restrict__ gi,
    float* __restrict__ out) {
  extern __shared__ char smem[];
  unsigned short* wlN = (unsigned short*)smem;              // 131072 B (N frags)
  unsigned short* hsb = (unsigned short*)(smem + 131072);   // 2 x 1024 ushorts
  float* scr = (float*)(smem + 135168);                     // 8 waves x 400 f
  unsigned char* msk = (unsigned char*)(smem + 147968);     // 128 B
  int* detf = (int*)(smem + 148096);                        // 12 B

  const int tid = threadIdx.x;
  const int b = blockIdx.x;
  const unsigned short* whh_b = wsb + K3 * II;

  if (tid < 3) detf[tid] = 0;
  for (int i = tid; i < 2048; i += 512) hsb[i] = 0;
  // N0,N1 tiles per wave -> LDS fragment order: wave w2, tile n, k-step kk,
  // lane l2: row = 512 + 32*w2 + 16*n + (l2&15), col = kk*32 + (l2>>4)*8
  for (int e = tid; e < 8192; e += 512) {
    int w2 = e >> 10, n = (e >> 9) & 1, kk = (e >> 6) & 7, l2 = e & 63;
    int row = 512 + 32 * w2 + 16 * n + (l2 & 15);
    int col = kk * 32 + (l2 >> 4) * 8;
    *(short8*)(wlN + (size_t)e * 8) = *(const short8*)&whh_b[(size_t)row * HH + col];
  }

  // ---- is_init layout probe (verified r1-r8 logic) ----
  {
    const unsigned int* wq = (const unsigned int*)init_raw;
    int notf = 0, gt1 = 0, oddnz = 0;
    for (int i = tid; i < (BB * TT / 4); i += 512) {
      unsigned int v = wq[i];
      notf |= (v != 0u && v != 0x3F800000u);
      gt1 |= (v > 1u);
      if (i & 1) oddnz |= (v != 0u);
    }
    if (notf) atomicOr(&detf[0], 1);
    if (gt1) atomicOr(&detf[1], 1);
    if (oddnz) atomicOr(&detf[2], 1);
  }
  __syncthreads();
  if (tid < TT) {
    int layout = (!detf[0]) ? 1 : (detf[1] ? 0 : (detf[2] ? 1 : 2));
    int e = b * TT + tid;
    unsigned int v;
    if (layout == 0)      v = ((const unsigned char*)init_raw)[e];
    else if (layout == 1) v = ((const unsigned int*)init_raw)[e];
    else                  v = ((const unsigned int*)init_raw)[2 * e];
    msk[tid] = v ? 1 : 0;
  }

  const int l = tid & 63, w = tid >> 6;
  const int c = l & 15, g = l >> 4;
  const bool act = (c < AA);

  // register tiles R0,R1,Z0,Z1 (gate-aligned): rows 32w+c, 32w+16+c,
  // 256+32w+c, 256+32w+16+c — short8 loads from bf16 ws (AGPR-friendly)
  short8 wreg[4][8];
#pragma unroll
  for (int q = 0; q < 4; ++q) {
    int row = (q >> 1) * 256 + 32 * w + (q & 1) * 16 + c;
#pragma unroll
    for (int kk = 0; kk < 8; ++kk)
      wreg[q][kk] = *(const short8*)&whh_b[(size_t)row * HH + kk * 32 + g * 8];
  }

  // pointwise mapping: agent a = g, units j0 = 32w + 2c, j0+1
  const int a = g;
  const int u2 = 2 * c;
  const int j0 = 32 * w + u2;
  const float2 bn2 = *(const float2*)&bhh_g[2 * HH + j0];

  __syncthreads();

  const unsigned short* gp = gi + ((size_t)(b * TT) * AA + a) * K3 + j0;
  float* op = out + ((size_t)(b * TT) * AA + a) * HH + j0;
  const unsigned short* hrd = hsb + ((c & 3) * 4 + g) * 8;   // + P*1024 + kk*128
  unsigned short* hwp = hsb + w * 128 + a * 32 + u2;         // + (1-P)*1024
  float* swp = scr + w * 400 + c * 100 + g * 4;              // wave-local scratch
  const float* srp = scr + w * 400 + a * 100 + u2;
  const unsigned short* wlp = wlN + w * 8192 + l * 8;        // + n*4096 + kk*512

  float h0 = 0.f, h1 = 0.f;
  unsigned int gcA[3], gcB[3];
  int mA, mB;
  const f32x4 Z4 = {0.f, 0.f, 0.f, 0.f};

#define GI_LOAD(GC)                               \
  do {                                            \
    GC[0] = *(const unsigned int*)(gp);           \
    GC[1] = *(const unsigned int*)(gp + 256);     \
    GC[2] = *(const unsigned int*)(gp + 512);     \
    gp += AA * K3;                                \
  } while (0)

#define L2E 1.44269504088896f

#define STEP(P, GC, MK)                                                           \
  do {                                                                            \
    float sR0, sR1, sZ0, sZ1, sN0, sN1;                                           \
    if ((MK) != 0) {                                                              \
      h0 = 0.f; h1 = 0.f;                                                         \
      sR0 = sR1 = sZ0 = sZ1 = sN0 = sN1 = 0.f;                                    \
    } else {                                                                      \
      short8 bhf[8];                                                              \
      _Pragma("unroll") for (int kk = 0; kk < 8; ++kk)                            \
          bhf[kk] = *(const short8*)(hrd + (P) * 1024 + kk * 128);                \
      f32x4 aR0 = __builtin_amdgcn_mfma_f32_16x16x32_bf16(wreg[0][0], bhf[0], Z4, 0, 0, 0); \
      f32x4 aR1 = __builtin_amdgcn_mfma_f32_16x16x32_bf16(wreg[1][0], bhf[0], Z4, 0, 0, 0); \
      f32x4 aZ0 = __builtin_amdgcn_mfma_f32_16x16x32_bf16(wreg[2][0], bhf[0], Z4, 0, 0, 0); \
      f32x4 aZ1 = __builtin_amdgcn_mfma_f32_16x16x32_bf16(wreg[3][0], bhf[0], Z4, 0, 0, 0); \
      f32x4 aN0 = __builtin_amdgcn_mfma_f32_16x16x32_bf16(                        \
          *(const short8*)(wlp), bhf[0], Z4, 0, 0, 0);                            \
      f32x4 aN1 = __builtin_amdgcn_mfma_f32_16x16x32_bf16(                        \
          *(const short8*)(wlp + 4096), bhf[0], Z4, 0, 0, 0);                     \
      _Pragma("unroll") for (int kk = 1; kk < 8; ++kk) {                          \
        aR0 = __builtin_amdgcn_mfma_f32_16x16x32_bf16(wreg[0][kk], bhf[kk], aR0, 0, 0, 0); \
        aR1 = __builtin_amdgcn_mfma_f32_16x16x32_bf16(wreg[1][kk], bhf[kk], aR1, 0, 0, 0); \
        aZ0 = __builtin_amdgcn_mfma_f32_16x16x32_bf16(wreg[2][kk], bhf[kk], aZ0, 0, 0, 0); \
        aZ1 = __builtin_amdgcn_mfma_f32_16x16x32_bf16(wreg[3][kk], bhf[kk], aZ1, 0, 0, 0); \
        aN0 = __builtin_amdgcn_mfma_f32_16x16x32_bf16(                            \
            *(const short8*)(wlp + kk * 512), bhf[kk], aN0, 0, 0, 0);             \
        aN1 = __builtin_amdgcn_mfma_f32_16x16x32_bf16(                            \
            *(const short8*)(wlp + 4096 + kk * 512), bhf[kk], aN1, 0, 0, 0);      \
      }                                                                           \
      if (act) {                                                                  \
        *(f32x4*)(swp + 0)  = aR0;                                                \
        *(f32x4*)(swp + 16) = aR1;                                                \
        *(f32x4*)(swp + 32) = aZ0;                                                \
        *(f32x4*)(swp + 48) = aZ1;                                                \
        *(f32x4*)(swp + 64) = aN0;                                                \
        *(f32x4*)(swp + 80) = aN1;                                                \
      }                                                                           \
      float2 vR = *(const float2*)(srp);                                          \
      float2 vZ = *(const float2*)(srp + 32);                                     \
      float2 vN = *(const float2*)(srp + 64);                                     \
      sR0 = vR.x; sR1 = vR.y; sZ0 = vZ.x; sZ1 = vZ.y; sN0 = vN.x; sN1 = vN.y;     \
    }                                                                             \
    const float gr0 = bf2f((unsigned short)(GC[0]));                              \
    const float gr1 = bf2f((unsigned short)(GC[0] >> 16));                        \
    const float gz0 = bf2f((unsigned short)(GC[1]));                              \
    const float gz1 = bf2f((unsigned short)(GC[1] >> 16));                        \
    const float gn0 = bf2f((unsigned short)(GC[2]));                              \
    const float gn1 = bf2f((unsigned short)(GC[2] >> 16));                        \
    const float rs0 = __builtin_amdgcn_rcpf(1.f + __builtin_amdgcn_exp2f(-(gr0 + sR0) * L2E)); \
    const float rs1 = __builtin_amdgcn_rcpf(1.f + __builtin_amdgcn_exp2f(-(gr1 + sR1) * L2E)); \
    const float zs0 = __builtin_amdgcn_rcpf(1.f + __builtin_amdgcn_exp2f(-(gz0 + sZ0) * L2E)); \
    const float zs1 = __builtin_amdgcn_rcpf(1.f + __builtin_amdgcn_exp2f(-(gz1 + sZ1) * L2E)); \
    const float pre0 = gn0 + rs0 * (sN0 + bn2.x);                                 \
    const float pre1 = gn1 + rs1 * (sN1 + bn2.y);                                 \
    const float nn0 = 1.f - 2.f * __builtin_amdgcn_rcpf(1.f + __builtin_amdgcn_exp2f(pre0 * (2.f * L2E))); \
    const float nn1 = 1.f - 2.f * __builtin_amdgcn_rcpf(1.f + __builtin_amdgcn_exp2f(pre1 * (2.f * L2E))); \
    h0 = fmaf(zs0, h0 - nn0, nn0);                                                \
    h1 = fmaf(zs1, h1 - nn1, nn1);                                                \
    unsigned int hw = (unsigned int)f2bf(h0) | ((unsigned int)f2bf(h1) << 16);    \
    *(unsigned int*)(hwp + (1 - (P)) * 1024) = hw;                                \
    float2 o2; o2.x = h0; o2.y = h1;                                              \
    *(float2*)op = o2;                                                            \
    op += AA * HH;                                                                \
    LGKM_BARRIER();                                                               \
  } while (0)

  GI_LOAD(gcA);  // t = 0
  mA = msk[0];
  for (int t = 0; t < TT - 2; t += 2) {
    GI_LOAD(gcB);  // t+1
    mB = msk[t + 1];
    STEP(0, gcA, mA);
    GI_LOAD(gcA);  // t+2
    mA = msk[t + 2];
    STEP(1, gcB, mB);
  }
  {
    GI_LOAD(gcB);  // t = 127
    mB = msk[TT - 1];
    STEP(0, gcA, mA);
    STEP(1, gcB, mB);
  }

  {
    float* hp = out + (size_t)BB * TT * AA * HH + ((size_t)b * AA + a) * HH + j0;
    float2 o2; o2.x = h0; o2.y = h1;
    *(float2*)hp = o2;
  }
#undef GI_LOAD
#undef STEP
}

// ---------------- Fallback: round-1 kernel (known-pass) ----------------
template <int WSW>
__global__ __launch_bounds__(512, 2) void gru_kernel(
    const float* __restrict__ x,
    const void* __restrict__ init_raw,
    const float* __restrict__ wih_f,
    const float* __restrict__ whh_f,
    const float* __restrict__ bih_g,
    const float* __restrict__ bhh_g,
    const unsigned short* __restrict__ wb,
    float* __restrict__ out) {
  __shared__ alignas(16) unsigned short xs[AA][II + 8];
  __shared__ alignas(16) unsigned short hsb[AA][HH + 8];
  __shared__ float hs32[AA][HH];
  __shared__ float gi_s[K3][5];
  __shared__ float gh_s[K3][5];
  __shared__ float bihs[K3];
  __shared__ float bhhs[K3];
  __shared__ unsigned char msk[TT];
  __shared__ int detf[3];

  const int tid = threadIdx.x;
  const int b = blockIdx.x;

  if (tid < 3) detf[tid] = 0;
  for (int i = tid; i < K3; i += 512) { bihs[i] = bih_g[i]; bhhs[i] = bhh_g[i]; }
  for (int i = tid; i < AA * HH; i += 512) {
    hs32[i >> 8][i & 255] = 0.f;
    hsb[i >> 8][i & 255] = 0;
  }
  __syncthreads();
  {
    const unsigned int* wq = (const unsigned int*)init_raw;
    int notf = 0, gt1 = 0, oddnz = 0;
    for (int i = tid; i < (BB * TT / 4); i += 512) {
      unsigned int v = wq[i];
      notf |= (v != 0u && v != 0x3F800000u);
      gt1 |= (v > 1u);
      if (i & 1) oddnz |= (v != 0u);
    }
    if (notf) atomicOr(&detf[0], 1);
    if (gt1) atomicOr(&detf[1], 1);
    if (oddnz) atomicOr(&detf[2], 1);
  }
  __syncthreads();
  if (tid < TT) {
    int layout = (!detf[0]) ? 1 : (detf[1] ? 0 : (detf[2] ? 1 : 2));
    int e = b * TT + tid;
    unsigned int v;
    if (layout == 0)      v = ((const unsigned char*)init_raw)[e];
    else if (layout == 1) v = ((const unsigned int*)init_raw)[e];
    else                  v = ((const unsigned int*)init_raw)[2 * e];
    msk[tid] = v ? 1 : 0;
  }
  __syncthreads();

  const int l = tid & 63;
  const int w = tid >> 6;
  const int c = l & 15;
  const int g = l >> 4;
  const bool act = (c < AA);
  const int xa = tid >> 7, xi = tid & 127;
  const float* xrow = x + (size_t)b * TT * AA * II;
  const unsigned short* wihb = wb;
  const unsigned short* whhb = wb + K3 * II;

  for (int t = 0; t < TT; ++t) {
    xs[xa][xi] = f2bf(xrow[(size_t)t * (AA * II) + tid]);
    if (msk[t]) {
      for (int i = tid; i < AA * HH; i += 512) {
        hs32[i >> 8][i & 255] = 0.f;
        hsb[i >> 8][i & 255] = 0;
      }
    }
    __syncthreads();

    short8 bx[4], bh[8];
    if (act) {
#pragma unroll
      for (int kk = 0; kk < 4; ++kk) bx[kk] = *(const short8*)&xs[c][kk * 32 + g * 8];
#pragma unroll
      for (int kk = 0; kk < 8; ++kk) bh[kk] = *(const short8*)&hsb[c][kk * 32 + g * 8];
    } else {
#pragma unroll
      for (int kk = 0; kk < 4; ++kk) bx[kk] = (short8)0;
#pragma unroll
      for (int kk = 0; kk < 8; ++kk) bh[kk] = (short8)0;
    }

#pragma unroll
    for (int kt = 0; kt < 6; ++kt) {
      const int ar = w * 96 + kt * 16 + c;
      f32x4 acc = {0.f, 0.f, 0.f, 0.f};
#pragma unroll
      for (int kk = 0; kk < 4; ++kk) {
        short8 aw;
        if (WSW) {
          aw = *(const short8*)&wihb[(size_t)ar * II + kk * 32 + g * 8];
        } else {
          const float* p = &wih_f[(size_t)ar * II + kk * 32 + g * 8];
#pragma unroll
          for (int e = 0; e < 8; ++e) aw[e] = (short)f2bf(p[e]);
        }
        acc = __builtin_amdgcn_mfma_f32_16x16x32_bf16(aw, bx[kk], acc, 0, 0, 0);
      }
      if (act) {
        const int dr = w * 96 + kt * 16 + g * 4;
#pragma unroll
        for (int r = 0; r < 4; ++r) gi_s[dr + r][c] = acc[r];
      }
    }

#pragma unroll
    for (int kt = 0; kt < 6; ++kt) {
      const int ar = w * 96 + kt * 16 + c;
      f32x4 acc = {0.f, 0.f, 0.f, 0.f};
#pragma unroll
      for (int kk = 0; kk < 8; ++kk) {
        short8 aw;
        if (WSW) {
          aw = *(const short8*)&whhb[(size_t)ar * HH + kk * 32 + g * 8];
        } else {
          const float* p = &whh_f[(size_t)ar * HH + kk * 32 + g * 8];
#pragma unroll
          for (int e = 0; e < 8; ++e) aw[e] = (short)f2bf(p[e]);
        }
        acc = __builtin_amdgcn_mfma_f32_16x16x32_bf16(aw, bh[kk], acc, 0, 0, 0);
      }
      if (act) {
        const int dr = w * 96 + kt * 16 + g * 4;
#pragma unroll
        for (int r = 0; r < 4; ++r) gh_s[dr + r][c] = acc[r];
      }
    }
    __syncthreads();

#pragma unroll
    for (int it = 0; it < 2; ++it) {
      const int idx = it * 512 + tid;
      const int a = idx >> 8, j = idx & 255;
      const float ir = gi_s[j][a] + bihs[j];
      const float iz = gi_s[HH + j][a] + bihs[HH + j];
      const float inn = gi_s[2 * HH + j][a] + bihs[2 * HH + j];
      const float hr = gh_s[j][a] + bhhs[j];
      const float hz = gh_s[HH + j][a] + bhhs[HH + j];
      const float hn = gh_s[2 * HH + j][a] + bhhs[2 * HH + j];
      const float r = 1.f / (1.f + __expf(-(ir + hr)));
      const float z = 1.f / (1.f + __expf(-(iz + hz)));
      const float pre = inn + r * hn;
      const float ea = __expf(-2.f * fabsf(pre));
      float n = (1.f - ea) / (1.f + ea);
      n = (pre < 0.f) ? -n : n;
      const float hold = hs32[a][j];
      const float hnew = (1.f - z) * n + z * hold;
      hs32[a][j] = hnew;
      hsb[a][j] = f2bf(hnew);
      out[(((size_t)b * TT + t) * AA + a) * HH + j] = hnew;
      if (t == TT - 1)
        out[(size_t)BB * TT * AA * HH + ((size_t)b * AA + a) * HH + j] = hnew;
    }
    __syncthreads();
  }
}

extern "C" void kernel_launch(void* const* d_in, const int* in_sizes, int n_in,
                              void* d_out, int out_size, void* d_ws, size_t ws_size,
                              hipStream_t stream) {
  (void)in_sizes; (void)n_in; (void)out_size;
  const float* x = (const float*)d_in[0];
  const void* is_init = d_in[1];
  const float* wih = (const float*)d_in[2];
  const float* whh = (const float*)d_in[3];
  const float* bih = (const float*)d_in[4];
  const float* bhh = (const float*)d_in[5];
  float* out = (float*)d_out;

  const size_t W_ELS = (size_t)(K3 * II + K3 * HH);        // 294,912
  const size_t W_BYTES = W_ELS * 2;                        // 589,824
  const size_t GI_BYTES = (size_t)BB * TT * AA * K3 * 2;   // 201,326,592
  const int SMEM = 148112;

  if (ws_size >= W_BYTES + GI_BYTES) {
    hipError_t e = hipFuncSetAttribute(
        (const void*)rnn_kernel, hipFuncAttributeMaxDynamicSharedMemorySize, SMEM);
    if (e == hipSuccess) {
      unsigned short* wb = (unsigned short*)d_ws;
      unsigned short* gi = wb + W_ELS;
      wconv_kernel<<<(int)(W_ELS / 512), 512, 0, stream>>>(wih, whh, wb);
      gi_kernel<<<2048, 512, 0, stream>>>(x, bih, bhh, wb, gi);
      rnn_kernel<<<BB, 512, SMEM, stream>>>(is_init, bhh, wb, gi, out);
      return;
    }
  }
  // fallback (round-1 verified path)
  if (ws_size >= W_BYTES) {
    unsigned short* wb = (unsigned short*)d_ws;
    wconv_kernel<<<(int)(W_ELS / 512), 512, 0, stream>>>(wih, whh, wb);
    gru_kernel<1><<<BB, 512, 0, stream>>>(x, is_init, wih, whh, bih, bhh, wb, out);
  } else {
    gru_kernel<0><<<BB, 512, 0, stream>>>(x, is_init, wih, whh, bih, bhh, nullptr, out);
  }
}